// Round 2
// baseline (8604.901 us; speedup 1.0000x reference)
//
#include <hip/hip_runtime.h>

// Problem constants
#define H_    128
#define W_    128
#define C_    3
#define KH_   32
#define KW_   32
#define PAD_  10
#define LWID  117          // LW = LH = 117
#define L_    13689        // LH*LW
#define D_    3072         // C*KH*KW
#define NMEM_ 4096

// GEMM tiling
#define TL 128
#define TN 128
#define BK 32

// Static device-side scratch — no d_ws dependency (previous round's abort was
// most plausibly a d_ws overflow: we needed ~389 KB without checking ws_size).
__device__ unsigned long long g_best[L_];
__device__ float              g_bias[NMEM_];
__device__ unsigned           g_max;

__device__ __forceinline__ unsigned sortable(float f) {
    unsigned b = __float_as_uint(f);
    return (b & 0x80000000u) ? ~b : (b | 0x80000000u);
}
__device__ __forceinline__ float unsortable(unsigned u) {
    unsigned b = (u & 0x80000000u) ? (u & 0x7FFFFFFFu) : ~u;
    return __uint_as_float(b);
}

// ---- init: zero the atomically-merged scratch every call --------------------
__global__ __launch_bounds__(256)
void init_kernel()
{
    int i = blockIdx.x * 256 + threadIdx.x;
    if (i < L_) g_best[i] = 0ull;
    if (i == 0) g_max = 0u;
}

// ---- bias[n] = -0.5 * ||mem[n]||^2 ------------------------------------------
__global__ __launch_bounds__(256)
void bias_kernel(const float* __restrict__ mem)
{
    int n = blockIdx.x;
    const float* row = mem + (size_t)n * D_;
    float s = 0.f;
    for (int d = threadIdx.x; d < D_; d += 256) {
        float v = row[d];
        s = fmaf(v, v, s);
    }
    #pragma unroll
    for (int m = 32; m >= 1; m >>= 1) s += __shfl_down(s, m, 64);
    __shared__ float red[4];
    int lane = threadIdx.x & 63, w = threadIdx.x >> 6;
    if (lane == 0) red[w] = s;
    __syncthreads();
    if (threadIdx.x == 0) g_bias[n] = -0.5f * (red[0] + red[1] + red[2] + red[3]);
}

// ---- fused scores GEMM + row argmax -----------------------------------------
// scores[l][n] = dot(patch_l, mem_n) + bias[n]; g_best[l] = packed argmax key.
// A (patches) built on the fly from the image (zero padding handled inline).
__global__ __launch_bounds__(256)
void gemm_argmax(const float* __restrict__ img,
                 const float* __restrict__ mem)
{
    __shared__ float As[BK][TL];   // [k][l-row]
    __shared__ float Bs[BK][TN];   // [k][n-col]
    __shared__ float biasS[TN];

    const int tid = threadIdx.x;
    const int l0 = blockIdx.y * TL;
    const int n0 = blockIdx.x * TN;

    if (tid < TN) biasS[tid] = g_bias[n0 + tid];

    const int tx = tid & 15, ty = tid >> 4;
    const int ry = ty * 8, cx = tx * 8;

    float acc[8][8];
    #pragma unroll
    for (int i = 0; i < 8; i++)
        #pragma unroll
        for (int j = 0; j < 8; j++) acc[i][j] = 0.f;

    const int sr = tid >> 3;        // 0..31  (staging row)
    const int sd = (tid & 7) * 4;   // 0..28  (staging k offset, 4 consecutive)

    int pys[4], pxs[4], lval[4];
    #pragma unroll
    for (int p = 0; p < 4; p++) {
        int l = l0 + sr + p * 32;
        lval[p] = l;
        int py = l / LWID;
        pys[p] = py;
        pxs[p] = l - py * LWID;
    }

    for (int d0 = 0; d0 < D_; d0 += BK) {
        __syncthreads();
        // stage B: mem rows are K-contiguous -> coalesced float4 loads
        {
            const float* bp = mem + (size_t)(n0 + sr) * D_ + d0 + sd;
            #pragma unroll
            for (int p = 0; p < 4; p++) {
                float4 v = *(const float4*)(bp + (size_t)p * 32 * D_);
                int r = sr + p * 32;
                Bs[sd + 0][r] = v.x; Bs[sd + 1][r] = v.y;
                Bs[sd + 2][r] = v.z; Bs[sd + 3][r] = v.w;
            }
        }
        // stage A: on-the-fly unfold. d = d0+sd+q -> (c, kh, kw0+q); c,kh
        // constant across the 4-group since sd is 4-aligned within a 32-block.
        {
            int d   = d0 + sd;
            int c   = d >> 10;
            int rem = d & 1023;
            int kh  = rem >> 5;
            int kw0 = rem & 31;
            #pragma unroll
            for (int p = 0; p < 4; p++) {
                float v[4] = {0.f, 0.f, 0.f, 0.f};
                if (lval[p] < L_) {
                    int y = pys[p] + kh - PAD_;
                    if ((unsigned)y < (unsigned)H_) {
                        int xb = pxs[p] + kw0 - PAD_;
                        const float* ip = img + (size_t)y * (W_ * C_) + c;
                        #pragma unroll
                        for (int q = 0; q < 4; q++) {
                            int x = xb + q;
                            if ((unsigned)x < (unsigned)W_) v[q] = ip[x * C_];
                        }
                    }
                }
                int r = sr + p * 32;
                As[sd + 0][r] = v[0]; As[sd + 1][r] = v[1];
                As[sd + 2][r] = v[2]; As[sd + 3][r] = v[3];
            }
        }
        __syncthreads();
        // compute 8x8 per thread
        #pragma unroll
        for (int k = 0; k < BK; k++) {
            float a[8], b[8];
            *(float4*)&a[0] = *(const float4*)&As[k][ry];
            *(float4*)&a[4] = *(const float4*)&As[k][ry + 4];
            *(float4*)&b[0] = *(const float4*)&Bs[k][cx];
            *(float4*)&b[4] = *(const float4*)&Bs[k][cx + 4];
            #pragma unroll
            for (int i = 0; i < 8; i++)
                #pragma unroll
                for (int j = 0; j < 8; j++)
                    acc[i][j] = fmaf(a[i], b[j], acc[i][j]);
        }
    }

    // epilogue: per-row argmax over this tile's 128 columns.
    // key = (sortable(score) << 32) | ~n : max-key == max score, ties -> min n
    // (matches jnp.argmax first-index semantics).
    unsigned long long keys[8];
    #pragma unroll
    for (int i = 0; i < 8; i++) {
        float bs = acc[i][0] + biasS[cx];
        int bj = 0;
        #pragma unroll
        for (int j = 1; j < 8; j++) {
            float s = acc[i][j] + biasS[cx + j];
            if (s > bs) { bs = s; bj = j; }
        }
        unsigned n = (unsigned)(n0 + cx + bj);
        keys[i] = ((unsigned long long)sortable(bs) << 32) | (unsigned)(~n);
    }
    #pragma unroll
    for (int m = 1; m < 16; m <<= 1) {
        #pragma unroll
        for (int i = 0; i < 8; i++) {
            unsigned long long o = __shfl_xor(keys[i], m, 64);
            if (o > keys[i]) keys[i] = o;
        }
    }
    if (tx == 0) {
        #pragma unroll
        for (int i = 0; i < 8; i++) {
            int l = l0 + ry + i;
            if (l < L_) atomicMax(g_best + l, keys[i]);
        }
    }
}

// ---- fold: scatter mem2[mapping[ks]] straight into the cropped output -------
// Reference crops [PAD:PAD+H] after fold, so out-of-crop contributions are
// simply dropped — no padded intermediate needed.
__global__ __launch_bounds__(256)
void fold_scatter(const int* __restrict__ mapping,
                  const float* __restrict__ mem2,
                  float* __restrict__ out)
{
    int l = blockIdx.x;
    unsigned long long key = g_best[l];
    int n = (int)(~(unsigned)(key & 0xFFFFFFFFull)) & (NMEM_ - 1);
    int pat = mapping[n];
    const float* row = mem2 + (size_t)pat * D_;
    int py = l / LWID, px = l - (l / LWID) * LWID;
    for (int d = threadIdx.x; d < D_; d += 256) {
        int c = d >> 10, rem = d & 1023, kh = rem >> 5, kw = rem & 31;
        int y = py + kh - PAD_;
        int x = px + kw - PAD_;
        if ((unsigned)y < (unsigned)H_ && (unsigned)x < (unsigned)W_)
            atomicAdd(out + ((size_t)y * W_ + x) * C_ + c, row[d]);
    }
}

// ---- global max over out ----------------------------------------------------
__global__ __launch_bounds__(256)
void maxfind(const float* __restrict__ out)
{
    int i = blockIdx.x * 256 + threadIdx.x;
    float v = (i < H_ * W_ * C_) ? out[i] : -3.4e38f;
    #pragma unroll
    for (int s = 32; s >= 1; s >>= 1) v = fmaxf(v, __shfl_xor(v, s, 64));
    if ((threadIdx.x & 63) == 0) atomicMax(&g_max, sortable(v));
}

__global__ __launch_bounds__(256)
void normalize_k(float* __restrict__ out)
{
    int i = blockIdx.x * 256 + threadIdx.x;
    if (i >= H_ * W_ * C_) return;
    float mx = unsortable(g_max);
    out[i] = out[i] / mx;
}

extern "C" void kernel_launch(void* const* d_in, const int* in_sizes, int n_in,
                              void* d_out, int out_size, void* d_ws, size_t ws_size,
                              hipStream_t stream)
{
    const float* img     = (const float*)d_in[0];   // (128,128,3)
    const float* mem     = (const float*)d_in[1];   // (4096,3072)
    const float* mem2    = (const float*)d_in[2];   // (4096,3072)
    const int*   mapping = (const int*)d_in[3];     // (4096,)
    float* out = (float*)d_out;                     // (128,128,3)

    // d_out is poisoned 0xAA before every launch — zero it (fold accumulates).
    hipMemsetAsync(d_out, 0, (size_t)out_size * sizeof(float), stream);

    init_kernel<<<(L_ + 255) / 256, 256, 0, stream>>>();
    bias_kernel<<<NMEM_, 256, 0, stream>>>(mem);
    gemm_argmax<<<dim3(NMEM_ / TN, (L_ + TL - 1) / TL), 256, 0, stream>>>(img, mem);
    fold_scatter<<<L_, 256, 0, stream>>>(mapping, mem2, out);
    maxfind<<<(H_ * W_ * C_ + 255) / 256, 256, 0, stream>>>(out);
    normalize_k<<<(H_ * W_ * C_ + 255) / 256, 256, 0, stream>>>(out);
}

// Round 3
// 2407.454 us; speedup vs baseline: 3.5743x; 3.5743x over previous
//
#include <hip/hip_runtime.h>

// Problem constants
#define H_    128
#define W_    128
#define C_    3
#define PAD_  10
#define LWID  117          // LW = LH = 117
#define L_    13689        // LH*LW
#define LPAD  13696        // 107 * 128
#define D_    3072         // C*KH*KW
#define NMEM_ 4096

typedef _Float16 half4 __attribute__((ext_vector_type(4)));
typedef _Float16 half8 __attribute__((ext_vector_type(8)));
typedef float   floatx4 __attribute__((ext_vector_type(4)));

// Static device-side scratch (bss, allocated at module load — no d_ws dependency)
__device__ unsigned long long g_best[L_];
__device__ float              g_bias[NMEM_];
__device__ unsigned           g_max;
__device__ _Float16           g_Ah[(size_t)LPAD * D_];   // 84 MB
__device__ _Float16           g_Al[(size_t)LPAD * D_];   // 84 MB
__device__ _Float16           g_Bh[(size_t)NMEM_ * D_];  // 25 MB
__device__ _Float16           g_Bl[(size_t)NMEM_ * D_];  // 25 MB

__device__ __forceinline__ unsigned sortable(float f) {
    unsigned b = __float_as_uint(f);
    return (b & 0x80000000u) ? ~b : (b | 0x80000000u);
}
__device__ __forceinline__ float unsortable(unsigned u) {
    unsigned b = (u & 0x80000000u) ? (u & 0x7FFFFFFFu) : ~u;
    return __uint_as_float(b);
}

// async global->LDS, 16 bytes per lane (global_load_lds_dwordx4)
__device__ __forceinline__ void gl_lds16(const _Float16* g, _Float16* l) {
    __builtin_amdgcn_global_load_lds(
        (const __attribute__((address_space(1))) unsigned int*)(g),
        (__attribute__((address_space(3))) unsigned int*)(l), 16, 0, 0);
}

// ---- init: zero the atomically-merged scratch every call --------------------
__global__ __launch_bounds__(256)
void init_kernel()
{
    int i = blockIdx.x * 256 + threadIdx.x;
    if (i < L_) g_best[i] = 0ull;
    if (i == 0) g_max = 0u;
}

// ---- split mem -> (Bh, Bl) fp16 + bias[n] = -0.5*||mem[n]||^2 ---------------
__global__ __launch_bounds__(256)
void split_mem(const float* __restrict__ mem)
{
    int n = blockIdx.x;
    const float4* row = (const float4*)(mem + (size_t)n * D_);
    half4* bh = (half4*)(g_Bh + (size_t)n * D_);
    half4* bl = (half4*)(g_Bl + (size_t)n * D_);
    float s = 0.f;
    for (int q = threadIdx.x; q < D_ / 4; q += 256) {
        float4 v = row[q];
        half4 h, lo;
        h.x = (_Float16)v.x; h.y = (_Float16)v.y; h.z = (_Float16)v.z; h.w = (_Float16)v.w;
        lo.x = (_Float16)(v.x - (float)h.x); lo.y = (_Float16)(v.y - (float)h.y);
        lo.z = (_Float16)(v.z - (float)h.z); lo.w = (_Float16)(v.w - (float)h.w);
        bh[q] = h; bl[q] = lo;
        s = fmaf(v.x, v.x, s); s = fmaf(v.y, v.y, s);
        s = fmaf(v.z, v.z, s); s = fmaf(v.w, v.w, s);
    }
    #pragma unroll
    for (int m = 32; m >= 1; m >>= 1) s += __shfl_down(s, m, 64);
    __shared__ float red[4];
    int lane = threadIdx.x & 63, w = threadIdx.x >> 6;
    if (lane == 0) red[w] = s;
    __syncthreads();
    if (threadIdx.x == 0) g_bias[n] = -0.5f * (red[0] + red[1] + red[2] + red[3]);
}

// ---- materialize unfolded patches -> (Ah, Al) fp16 --------------------------
__global__ __launch_bounds__(256)
void build_patches(const float* __restrict__ img)
{
    int l = blockIdx.x;                 // 0..LPAD-1 (pad rows -> zeros)
    int py = l / LWID, px = l - (l / LWID) * LWID;
    bool vl = l < L_;
    half4* ah = (half4*)(g_Ah + (size_t)l * D_);
    half4* al = (half4*)(g_Al + (size_t)l * D_);
    for (int q = threadIdx.x; q < D_ / 4; q += 256) {
        int d = q * 4;
        int c = d >> 10, rem = d & 1023, kh = rem >> 5, kw0 = rem & 31;
        float v[4] = {0.f, 0.f, 0.f, 0.f};
        if (vl) {
            int y = py + kh - PAD_;
            if ((unsigned)y < (unsigned)H_) {
                int xb = px + kw0 - PAD_;
                const float* ip = img + (size_t)y * (W_ * C_) + c;
                #pragma unroll
                for (int t = 0; t < 4; t++) {
                    int x = xb + t;
                    if ((unsigned)x < (unsigned)W_) v[t] = ip[x * C_];
                }
            }
        }
        half4 h, lo;
        h.x = (_Float16)v[0]; h.y = (_Float16)v[1]; h.z = (_Float16)v[2]; h.w = (_Float16)v[3];
        lo.x = (_Float16)(v[0] - (float)h.x); lo.y = (_Float16)(v[1] - (float)h.y);
        lo.z = (_Float16)(v[2] - (float)h.z); lo.w = (_Float16)(v[3] - (float)h.w);
        ah[q] = h; al[q] = lo;
    }
}

// ---- MFMA GEMM (fp16 hi/lo 3-pass) + fused row argmax -----------------------
// C[l][n] = patch_l . mem_n  ~=  Ah.Bh + Ah.Bl + Al.Bh  (fp32 accum)
// 128x128 tile, BK=32, mfma_f32_16x16x32_f16, m97-style global_load_lds staging.
__global__ __launch_bounds__(256)
void gemm_argmax()
{
    __shared__ _Float16 sA0[128 * 32], sA1[128 * 32];
    __shared__ _Float16 sB0[128 * 32], sB1[128 * 32];
    __shared__ float biasS[128];

    const int tid = threadIdx.x;
    const int l0 = blockIdx.y * 128;
    const int n0 = blockIdx.x * 128;

    if (tid < 128) biasS[tid] = g_bias[n0 + tid];

    const int wave = tid >> 6, lane = tid & 63;
    const int wy = wave >> 1, wx = wave & 1;      // 2x2 wave grid, 64x64 each
    const int mrow = lane & 15, kgrp = lane >> 4; // MFMA A/B frag addressing

    floatx4 acc[4][4];
    #pragma unroll
    for (int i = 0; i < 4; i++)
        #pragma unroll
        for (int j = 0; j < 4; j++) acc[i][j] = (floatx4){0.f, 0.f, 0.f, 0.f};

    // staging chunks: 512 x 16B per 8KB tile; chunk c -> row=c>>2, kc=c&3
    const int c0 = tid, c1 = tid + 256;
    const int row0 = c0 >> 2, kc0 = c0 & 3;
    const int row1 = c1 >> 2, kc1 = c1 & 3;
    const _Float16* Ahb = g_Ah + (size_t)l0 * D_;
    const _Float16* Alb = g_Al + (size_t)l0 * D_;
    const _Float16* Bhb = g_Bh + (size_t)n0 * D_;
    const _Float16* Blb = g_Bl + (size_t)n0 * D_;

    for (int d0 = 0; d0 < D_; d0 += 32) {
        __syncthreads();
        {
            size_t go0 = (size_t)row0 * D_ + d0 + kc0 * 8;
            size_t go1 = (size_t)row1 * D_ + d0 + kc1 * 8;
            gl_lds16(Ahb + go0, &sA0[c0 * 8]);
            gl_lds16(Ahb + go1, &sA0[c1 * 8]);
            gl_lds16(Alb + go0, &sA1[c0 * 8]);
            gl_lds16(Alb + go1, &sA1[c1 * 8]);
            gl_lds16(Bhb + go0, &sB0[c0 * 8]);
            gl_lds16(Bhb + go1, &sB0[c1 * 8]);
            gl_lds16(Blb + go0, &sB1[c0 * 8]);
            gl_lds16(Blb + go1, &sB1[c1 * 8]);
        }
        __syncthreads();

        half8 ah[4], al[4], bh[4], bl[4];
        #pragma unroll
        for (int i = 0; i < 4; i++) {
            int ra = (wy * 64 + i * 16 + mrow) * 32 + kgrp * 8;
            int rb = (wx * 64 + i * 16 + mrow) * 32 + kgrp * 8;
            ah[i] = *(const half8*)&sA0[ra];
            al[i] = *(const half8*)&sA1[ra];
            bh[i] = *(const half8*)&sB0[rb];
            bl[i] = *(const half8*)&sB1[rb];
        }
        #pragma unroll
        for (int i = 0; i < 4; i++)
            #pragma unroll
            for (int j = 0; j < 4; j++) {
                acc[i][j] = __builtin_amdgcn_mfma_f32_16x16x32_f16(ah[i], bh[j], acc[i][j], 0, 0, 0);
                acc[i][j] = __builtin_amdgcn_mfma_f32_16x16x32_f16(ah[i], bl[j], acc[i][j], 0, 0, 0);
                acc[i][j] = __builtin_amdgcn_mfma_f32_16x16x32_f16(al[i], bh[j], acc[i][j], 0, 0, 0);
            }
    }

    // epilogue: per output row, argmax over this block's 128 columns.
    // C/D layout (16x16x32): col = lane&15, row = (lane>>4)*4 + reg.
    // key = (sortable(score)<<32) | ~n : max-key == max score, ties -> min n.
    #pragma unroll
    for (int i = 0; i < 4; i++) {
        #pragma unroll
        for (int r = 0; r < 4; r++) {
            float bestv = acc[i][0][r] + biasS[wx * 64 + mrow];
            int bestj = 0;
            #pragma unroll
            for (int j = 1; j < 4; j++) {
                float s = acc[i][j][r] + biasS[wx * 64 + j * 16 + mrow];
                if (s > bestv) { bestv = s; bestj = j; }
            }
            unsigned n = (unsigned)(n0 + wx * 64 + bestj * 16 + mrow);
            unsigned long long key =
                ((unsigned long long)sortable(bestv) << 32) | (unsigned)(~n);
            #pragma unroll
            for (int m = 1; m < 16; m <<= 1) {
                unsigned long long o = __shfl_xor(key, m, 64);
                if (o > key) key = o;
            }
            if (mrow == 0) {
                int l = l0 + wy * 64 + i * 16 + kgrp * 4 + r;
                if (l < L_) atomicMax(g_best + l, key);
            }
        }
    }
}

// ---- fold: scatter mem2[mapping[ks]] straight into the cropped output -------
__global__ __launch_bounds__(256)
void fold_scatter(const int* __restrict__ mapping,
                  const float* __restrict__ mem2,
                  float* __restrict__ out)
{
    int l = blockIdx.x;
    unsigned long long key = g_best[l];
    int n = (int)(~(unsigned)(key & 0xFFFFFFFFull)) & (NMEM_ - 1);
    int pat = mapping[n];
    const float* row = mem2 + (size_t)pat * D_;
    int py = l / LWID, px = l - (l / LWID) * LWID;
    for (int d = threadIdx.x; d < D_; d += 256) {
        int c = d >> 10, rem = d & 1023, kh = rem >> 5, kw = rem & 31;
        int y = py + kh - PAD_;
        int x = px + kw - PAD_;
        if ((unsigned)y < (unsigned)H_ && (unsigned)x < (unsigned)W_)
            atomicAdd(out + ((size_t)y * W_ + x) * C_ + c, row[d]);
    }
}

// ---- global max over out ----------------------------------------------------
__global__ __launch_bounds__(256)
void maxfind(const float* __restrict__ out)
{
    int i = blockIdx.x * 256 + threadIdx.x;
    float v = (i < H_ * W_ * C_) ? out[i] : -3.4e38f;
    #pragma unroll
    for (int s = 32; s >= 1; s >>= 1) v = fmaxf(v, __shfl_xor(v, s, 64));
    if ((threadIdx.x & 63) == 0) atomicMax(&g_max, sortable(v));
}

__global__ __launch_bounds__(256)
void normalize_k(float* __restrict__ out)
{
    int i = blockIdx.x * 256 + threadIdx.x;
    if (i >= H_ * W_ * C_) return;
    float mx = unsortable(g_max);
    out[i] = out[i] / mx;
}

extern "C" void kernel_launch(void* const* d_in, const int* in_sizes, int n_in,
                              void* d_out, int out_size, void* d_ws, size_t ws_size,
                              hipStream_t stream)
{
    const float* img     = (const float*)d_in[0];   // (128,128,3)
    const float* mem     = (const float*)d_in[1];   // (4096,3072)
    const float* mem2    = (const float*)d_in[2];   // (4096,3072)
    const int*   mapping = (const int*)d_in[3];     // (4096,)
    float* out = (float*)d_out;                     // (128,128,3)

    // d_out is poisoned 0xAA before every launch — zero it (fold accumulates).
    hipMemsetAsync(d_out, 0, (size_t)out_size * sizeof(float), stream);

    init_kernel<<<(L_ + 255) / 256, 256, 0, stream>>>();
    split_mem<<<NMEM_, 256, 0, stream>>>(mem);
    build_patches<<<LPAD, 256, 0, stream>>>(img);
    gemm_argmax<<<dim3(NMEM_ / 128, LPAD / 128), 256, 0, stream>>>();
    fold_scatter<<<L_, 256, 0, stream>>>(mapping, mem2, out);
    maxfind<<<(H_ * W_ * C_ + 255) / 256, 256, 0, stream>>>(out);
    normalize_k<<<(H_ * W_ * C_ + 255) / 256, 256, 0, stream>>>(out);
}

// Round 4
// 1337.255 us; speedup vs baseline: 6.4347x; 1.8003x over previous
//
#include <hip/hip_runtime.h>

// Problem constants
#define H_    128
#define W_    128
#define C_    3
#define PAD_  10
#define LWID  117          // LW = LH = 117
#define L_    13689        // LH*LW
#define LPAD  13696        // 107 * 128
#define D_    3072         // C*KH*KW
#define NMEM_ 4096

#define SHIFT_   1536.0f   // re-centers scores (~ -1536 +- 150) for fp16 storage
#define T_MARGIN 4.0f      // rescue margin; certified worst-case fp16 dot err ~1.8

typedef _Float16 half4 __attribute__((ext_vector_type(4)));
typedef _Float16 half8 __attribute__((ext_vector_type(8)));
typedef float   floatx4 __attribute__((ext_vector_type(4)));

// Static device-side scratch (bss, allocated at module load — no d_ws dependency)
__device__ int      g_best[L_];
__device__ float    g_bias[NMEM_];
__device__ unsigned g_max;
__device__ _Float16 g_A[(size_t)LPAD * D_];    // 84 MB fp16 patches
__device__ _Float16 g_B[(size_t)NMEM_ * D_];   // 25 MB fp16 mem
__device__ _Float16 g_S[(size_t)LPAD * NMEM_]; // 112 MB fp16 biased scores

__device__ __forceinline__ unsigned sortable(float f) {
    unsigned b = __float_as_uint(f);
    return (b & 0x80000000u) ? ~b : (b | 0x80000000u);
}
__device__ __forceinline__ float unsortable(unsigned u) {
    unsigned b = (u & 0x80000000u) ? (u & 0x7FFFFFFFu) : ~u;
    return __uint_as_float(b);
}

// async global->LDS, 16 bytes per lane (global_load_lds_dwordx4)
__device__ __forceinline__ void gl_lds16(const _Float16* g, _Float16* l) {
    __builtin_amdgcn_global_load_lds(
        (const __attribute__((address_space(1))) unsigned int*)(g),
        (__attribute__((address_space(3))) unsigned int*)(l), 16, 0, 0);
}

// ---- init -------------------------------------------------------------------
__global__ void init_kernel() { g_max = 0u; }

// ---- mem -> fp16 + bias[n] = -0.5*||mem[n]||^2 ------------------------------
__global__ __launch_bounds__(256)
void split_mem(const float* __restrict__ mem)
{
    int n = blockIdx.x;
    const float4* row = (const float4*)(mem + (size_t)n * D_);
    half4* bh = (half4*)(g_B + (size_t)n * D_);
    float s = 0.f;
    for (int q = threadIdx.x; q < D_ / 4; q += 256) {
        float4 v = row[q];
        half4 h;
        h.x = (_Float16)v.x; h.y = (_Float16)v.y; h.z = (_Float16)v.z; h.w = (_Float16)v.w;
        bh[q] = h;
        s = fmaf(v.x, v.x, s); s = fmaf(v.y, v.y, s);
        s = fmaf(v.z, v.z, s); s = fmaf(v.w, v.w, s);
    }
    #pragma unroll
    for (int m = 32; m >= 1; m >>= 1) s += __shfl_down(s, m, 64);
    __shared__ float red[4];
    int lane = threadIdx.x & 63, w = threadIdx.x >> 6;
    if (lane == 0) red[w] = s;
    __syncthreads();
    if (threadIdx.x == 0) g_bias[n] = -0.5f * (red[0] + red[1] + red[2] + red[3]);
}

// ---- materialize unfolded patches -> fp16 -----------------------------------
__global__ __launch_bounds__(256)
void build_patches(const float* __restrict__ img)
{
    int l = blockIdx.x;                 // 0..LPAD-1 (pad rows -> zeros)
    int py = l / LWID, px = l - (l / LWID) * LWID;
    bool vl = l < L_;
    half4* ah = (half4*)(g_A + (size_t)l * D_);
    for (int q = threadIdx.x; q < D_ / 4; q += 256) {
        int d = q * 4;
        int c = d >> 10, rem = d & 1023, kh = rem >> 5, kw0 = rem & 31;
        float v[4] = {0.f, 0.f, 0.f, 0.f};
        if (vl) {
            int y = py + kh - PAD_;
            if ((unsigned)y < (unsigned)H_) {
                int xb = px + kw0 - PAD_;
                const float* ip = img + (size_t)y * (W_ * C_) + c;
                #pragma unroll
                for (int t = 0; t < 4; t++) {
                    int x = xb + t;
                    if ((unsigned)x < (unsigned)W_) v[t] = ip[x * C_];
                }
            }
        }
        half4 h;
        h.x = (_Float16)v[0]; h.y = (_Float16)v[1]; h.z = (_Float16)v[2]; h.w = (_Float16)v[3];
        ah[q] = h;
    }
}

// ---- single-pass fp16 MFMA GEMM, stores biased scores -----------------------
// g_S[l][n] = fp16( patch_l . mem_n (fp16 inputs, fp32 acc) + bias[n] + SHIFT )
__global__ __launch_bounds__(256)
void gemm_scores()
{
    __shared__ _Float16 sA[128 * 32];
    __shared__ _Float16 sB[128 * 32];
    __shared__ float biasS[128];

    const int tid = threadIdx.x;
    const int l0 = blockIdx.y * 128;
    const int n0 = blockIdx.x * 128;

    if (tid < 128) biasS[tid] = g_bias[n0 + tid];

    const int wave = tid >> 6, lane = tid & 63;
    const int wy = wave >> 1, wx = wave & 1;      // 2x2 wave grid, 64x64 each
    const int mrow = lane & 15, kgrp = lane >> 4;

    floatx4 acc[4][4];
    #pragma unroll
    for (int i = 0; i < 4; i++)
        #pragma unroll
        for (int j = 0; j < 4; j++) acc[i][j] = (floatx4){0.f, 0.f, 0.f, 0.f};

    // staging: 512 chunks x 16B per 8KB tile; chunk c -> row=c>>2, kc=c&3
    const int c0 = tid, c1 = tid + 256;
    const int row0 = c0 >> 2, kc0 = c0 & 3;
    const int row1 = c1 >> 2, kc1 = c1 & 3;
    const _Float16* Ab = g_A + (size_t)l0 * D_;
    const _Float16* Bb = g_B + (size_t)n0 * D_;

    for (int d0 = 0; d0 < D_; d0 += 32) {
        __syncthreads();
        size_t go0 = (size_t)row0 * D_ + d0 + kc0 * 8;
        size_t go1 = (size_t)row1 * D_ + d0 + kc1 * 8;
        gl_lds16(Ab + go0, &sA[c0 * 8]);
        gl_lds16(Ab + go1, &sA[c1 * 8]);
        gl_lds16(Bb + go0, &sB[c0 * 8]);
        gl_lds16(Bb + go1, &sB[c1 * 8]);
        __syncthreads();

        half8 a[4], b[4];
        #pragma unroll
        for (int i = 0; i < 4; i++) {
            a[i] = *(const half8*)&sA[(wy * 64 + i * 16 + mrow) * 32 + kgrp * 8];
            b[i] = *(const half8*)&sB[(wx * 64 + i * 16 + mrow) * 32 + kgrp * 8];
        }
        #pragma unroll
        for (int i = 0; i < 4; i++)
            #pragma unroll
            for (int j = 0; j < 4; j++)
                acc[i][j] = __builtin_amdgcn_mfma_f32_16x16x32_f16(a[i], b[j], acc[i][j], 0, 0, 0);
    }

    // store epilogue. C/D layout: col = lane&15, row = (lane>>4)*4 + reg.
    _Float16* Sb = g_S + (size_t)(l0 + wy * 64) * NMEM_ + n0 + wx * 64;
    #pragma unroll
    for (int i = 0; i < 4; i++) {
        #pragma unroll
        for (int r = 0; r < 4; r++) {
            int lrow = i * 16 + kgrp * 4 + r;
            #pragma unroll
            for (int j = 0; j < 4; j++) {
                float s = acc[i][j][r] + biasS[wx * 64 + j * 16 + mrow] + SHIFT_;
                Sb[(size_t)lrow * NMEM_ + j * 16 + mrow] = (_Float16)s;
            }
        }
    }
}

// ---- per-row max + margin-flag + exact fp32 rescore -------------------------
__global__ __launch_bounds__(256)
void reduce_rescue(const float* __restrict__ img, const float* __restrict__ mem)
{
    int l = blockIdx.x;
    int tid = threadIdx.x;
    int lane = tid & 63, wave = tid >> 6;

    __shared__ _Float16 sS[NMEM_];   // 8 KB
    __shared__ int      list[NMEM_]; // 16 KB (cannot overflow: each n once)
    __shared__ int      cnt;
    __shared__ float    redf[4];
    __shared__ float    smaxS;

    if (tid == 0) cnt = 0;
    // load this row's scores
    {
        const half8* src = (const half8*)(g_S + (size_t)l * NMEM_);
        half8* dst = (half8*)sS;
        for (int q = tid; q < NMEM_ / 8; q += 256) dst[q] = src[q];
    }
    __syncthreads();
    // block max
    float m = -3.4e38f;
    for (int n = tid; n < NMEM_; n += 256) m = fmaxf(m, (float)sS[n]);
    #pragma unroll
    for (int s = 32; s >= 1; s >>= 1) m = fmaxf(m, __shfl_xor(m, s, 64));
    if (lane == 0) redf[wave] = m;
    __syncthreads();
    if (tid == 0) smaxS = fmaxf(fmaxf(redf[0], redf[1]), fmaxf(redf[2], redf[3]));
    __syncthreads();
    float thr = smaxS - T_MARGIN;
    // flag candidates within margin of max
    for (int n = tid; n < NMEM_; n += 256)
        if ((float)sS[n] >= thr) { int p = atomicAdd(&cnt, 1); list[p] = n; }
    __syncthreads();

    int k = cnt;
    int py = l / LWID, px = l - (l / LWID) * LWID;
    float bestv = -3.4e38f; int bestn = 0x7FFFFFFF;
    for (int q = 0; q < k; q++) {
        int n = list[q];
        const float* mr = mem + (size_t)n * D_;
        float s = 0.f;
        for (int d = tid; d < D_; d += 256) {
            int c = d >> 10, rem = d & 1023, kh = rem >> 5, kw = rem & 31;
            int y = py + kh - PAD_, x = px + kw - PAD_;
            float p = ((unsigned)y < (unsigned)H_ && (unsigned)x < (unsigned)W_)
                      ? img[((size_t)y * W_ + x) * C_ + c] : 0.f;
            s = fmaf(p, mr[d], s);
        }
        #pragma unroll
        for (int sh = 32; sh >= 1; sh >>= 1) s += __shfl_xor(s, sh, 64);
        if (lane == 0) redf[wave] = s;
        __syncthreads();
        float tot = redf[0] + redf[1] + redf[2] + redf[3] + g_bias[n];
        __syncthreads();   // redf reused next iteration
        if (tot > bestv || (tot == bestv && n < bestn)) { bestv = tot; bestn = n; }
    }
    if (tid == 0) g_best[l] = bestn;
}

// ---- fold: scatter mem2[mapping[ks]] straight into the cropped output -------
__global__ __launch_bounds__(256)
void fold_scatter(const int* __restrict__ mapping,
                  const float* __restrict__ mem2,
                  float* __restrict__ out)
{
    int l = blockIdx.x;
    int n = g_best[l];
    int pat = mapping[n];
    const float* row = mem2 + (size_t)pat * D_;
    int py = l / LWID, px = l - (l / LWID) * LWID;
    for (int d = threadIdx.x; d < D_; d += 256) {
        int c = d >> 10, rem = d & 1023, kh = rem >> 5, kw = rem & 31;
        int y = py + kh - PAD_;
        int x = px + kw - PAD_;
        if ((unsigned)y < (unsigned)H_ && (unsigned)x < (unsigned)W_)
            atomicAdd(out + ((size_t)y * W_ + x) * C_ + c, row[d]);
    }
}

// ---- global max over out ----------------------------------------------------
__global__ __launch_bounds__(256)
void maxfind(const float* __restrict__ out)
{
    int i = blockIdx.x * 256 + threadIdx.x;
    float v = (i < H_ * W_ * C_) ? out[i] : -3.4e38f;
    #pragma unroll
    for (int s = 32; s >= 1; s >>= 1) v = fmaxf(v, __shfl_xor(v, s, 64));
    if ((threadIdx.x & 63) == 0) atomicMax(&g_max, sortable(v));
}

__global__ __launch_bounds__(256)
void normalize_k(float* __restrict__ out)
{
    int i = blockIdx.x * 256 + threadIdx.x;
    if (i >= H_ * W_ * C_) return;
    float mx = unsortable(g_max);
    out[i] = out[i] / mx;
}

extern "C" void kernel_launch(void* const* d_in, const int* in_sizes, int n_in,
                              void* d_out, int out_size, void* d_ws, size_t ws_size,
                              hipStream_t stream)
{
    const float* img     = (const float*)d_in[0];   // (128,128,3)
    const float* mem     = (const float*)d_in[1];   // (4096,3072)
    const float* mem2    = (const float*)d_in[2];   // (4096,3072)
    const int*   mapping = (const int*)d_in[3];     // (4096,)
    float* out = (float*)d_out;                     // (128,128,3)

    // d_out is poisoned 0xAA before every launch — zero it (fold accumulates).
    hipMemsetAsync(d_out, 0, (size_t)out_size * sizeof(float), stream);

    init_kernel<<<1, 1, 0, stream>>>();
    split_mem<<<NMEM_, 256, 0, stream>>>(mem);
    build_patches<<<LPAD, 256, 0, stream>>>(img);
    gemm_scores<<<dim3(NMEM_ / 128, LPAD / 128), 256, 0, stream>>>();
    reduce_rescue<<<L_, 256, 0, stream>>>(img, mem);
    fold_scatter<<<L_, 256, 0, stream>>>(mapping, mem2, out);
    maxfind<<<(H_ * W_ * C_ + 255) / 256, 256, 0, stream>>>(out);
    normalize_k<<<(H_ * W_ * C_ + 255) / 256, 256, 0, stream>>>(out);
}

// Round 5
// 1331.796 us; speedup vs baseline: 6.4611x; 1.0041x over previous
//
#include <hip/hip_runtime.h>

// Problem constants
#define H_    128
#define W_    128
#define C_    3
#define PAD_  10
#define LWID  117          // LW = LH = 117
#define L_    13689        // LH*LW
#define LPAD  13696        // 107 * 128
#define D_    3072         // C*KH*KW
#define NMEM_ 4096

#define T_MARGIN 3.0f      // candidate margin; certified fp16-dot err bound ~1.2, need >2x
#define CAP_     192       // per-row candidate list capacity (expected ~74)
#define SCAP_    64        // rescue shortlist capacity (expected ~1.4)

typedef _Float16 half4 __attribute__((ext_vector_type(4)));
typedef _Float16 half8 __attribute__((ext_vector_type(8)));
typedef float   floatx4 __attribute__((ext_vector_type(4)));

// Static device-side scratch (bss) — no d_ws dependency
__device__ int                g_best[L_];
__device__ float              g_bias[NMEM_];
__device__ unsigned           g_max;
__device__ int                g_cnt[LPAD];
__device__ unsigned long long g_list[(size_t)LPAD * CAP_];   // 21 MB
__device__ _Float16           g_A[(size_t)LPAD * D_];        // 84 MB fp16 patches
__device__ _Float16           g_B[(size_t)NMEM_ * D_];       // 25 MB fp16 mem

__device__ __forceinline__ unsigned sortable(float f) {
    unsigned b = __float_as_uint(f);
    return (b & 0x80000000u) ? ~b : (b | 0x80000000u);
}
__device__ __forceinline__ float unsortable(unsigned u) {
    unsigned b = (u & 0x80000000u) ? (u & 0x7FFFFFFFu) : ~u;
    return __uint_as_float(b);
}
__device__ __forceinline__ unsigned long long packkey(float s, int n) {
    // max-key == max score; ties -> smaller n (jnp.argmax first-index)
    return ((unsigned long long)sortable(s) << 32) | (unsigned)(~n);
}

// async global->LDS, 16 bytes per lane (global_load_lds_dwordx4)
__device__ __forceinline__ void gl_lds16(const _Float16* g, _Float16* l) {
    __builtin_amdgcn_global_load_lds(
        (const __attribute__((address_space(1))) unsigned int*)(g),
        (__attribute__((address_space(3))) unsigned int*)(l), 16, 0, 0);
}

// ---- init: zero per-row counters + global max -------------------------------
__global__ __launch_bounds__(256)
void init_kernel()
{
    int i = blockIdx.x * 256 + threadIdx.x;
    if (i < LPAD) g_cnt[i] = 0;
    if (i == 0) g_max = 0u;
}

// ---- mem -> fp16 + bias[n] = -0.5*||mem[n]||^2 ------------------------------
__global__ __launch_bounds__(256)
void split_mem(const float* __restrict__ mem)
{
    int n = blockIdx.x;
    const float4* row = (const float4*)(mem + (size_t)n * D_);
    half4* bh = (half4*)(g_B + (size_t)n * D_);
    float s = 0.f;
    for (int q = threadIdx.x; q < D_ / 4; q += 256) {
        float4 v = row[q];
        half4 h;
        h.x = (_Float16)v.x; h.y = (_Float16)v.y; h.z = (_Float16)v.z; h.w = (_Float16)v.w;
        bh[q] = h;
        s = fmaf(v.x, v.x, s); s = fmaf(v.y, v.y, s);
        s = fmaf(v.z, v.z, s); s = fmaf(v.w, v.w, s);
    }
    #pragma unroll
    for (int m = 32; m >= 1; m >>= 1) s += __shfl_down(s, m, 64);
    __shared__ float red[4];
    int lane = threadIdx.x & 63, w = threadIdx.x >> 6;
    if (lane == 0) red[w] = s;
    __syncthreads();
    if (threadIdx.x == 0) g_bias[n] = -0.5f * (red[0] + red[1] + red[2] + red[3]);
}

// ---- materialize unfolded patches -> fp16 -----------------------------------
__global__ __launch_bounds__(256)
void build_patches(const float* __restrict__ img)
{
    int l = blockIdx.x;                 // 0..LPAD-1 (pad rows -> zeros)
    int py = l / LWID, px = l - (l / LWID) * LWID;
    bool vl = l < L_;
    half4* ah = (half4*)(g_A + (size_t)l * D_);
    for (int q = threadIdx.x; q < D_ / 4; q += 256) {
        int d = q * 4;
        int c = d >> 10, rem = d & 1023, kh = rem >> 5, kw0 = rem & 31;
        float v[4] = {0.f, 0.f, 0.f, 0.f};
        if (vl) {
            int y = py + kh - PAD_;
            if ((unsigned)y < (unsigned)H_) {
                int xb = px + kw0 - PAD_;
                const float* ip = img + (size_t)y * (W_ * C_) + c;
                #pragma unroll
                for (int t = 0; t < 4; t++) {
                    int x = xb + t;
                    if ((unsigned)x < (unsigned)W_) v[t] = ip[x * C_];
                }
            }
        }
        half4 h;
        h.x = (_Float16)v[0]; h.y = (_Float16)v[1]; h.z = (_Float16)v[2]; h.w = (_Float16)v[3];
        ah[q] = h;
    }
}

// ---- fp16 MFMA GEMM + in-register candidate extraction ----------------------
// Instead of storing the 13696x4096 score matrix, each wave reduces its 64-col
// group max per row and appends candidates >= groupmax - T to g_list[row].
// Containment proof: groupmax <= globalmax, so score >= globalmax - T implies
// score >= groupmax - T; with T > 2*err_fp16 the true argmax is always listed.
__global__ __launch_bounds__(256)
void gemm_scores()
{
    __shared__ _Float16 sA[128 * 32];
    __shared__ _Float16 sB[128 * 32];
    __shared__ float biasS[128];

    const int tid = threadIdx.x;
    const int l0 = blockIdx.y * 128;
    const int n0 = blockIdx.x * 128;

    if (tid < 128) biasS[tid] = g_bias[n0 + tid];

    const int wave = tid >> 6, lane = tid & 63;
    const int wy = wave >> 1, wx = wave & 1;      // 2x2 wave grid, 64x64 each
    const int mrow = lane & 15, kgrp = lane >> 4;

    floatx4 acc[4][4];
    #pragma unroll
    for (int i = 0; i < 4; i++)
        #pragma unroll
        for (int j = 0; j < 4; j++) acc[i][j] = (floatx4){0.f, 0.f, 0.f, 0.f};

    // staging: 512 chunks x 16B per 8KB tile; chunk c -> row=c>>2, kc=c&3
    const int c0 = tid, c1 = tid + 256;
    const int row0 = c0 >> 2, kc0 = c0 & 3;
    const int row1 = c1 >> 2, kc1 = c1 & 3;
    const _Float16* Ab = g_A + (size_t)l0 * D_;
    const _Float16* Bb = g_B + (size_t)n0 * D_;

    for (int d0 = 0; d0 < D_; d0 += 32) {
        __syncthreads();
        size_t go0 = (size_t)row0 * D_ + d0 + kc0 * 8;
        size_t go1 = (size_t)row1 * D_ + d0 + kc1 * 8;
        gl_lds16(Ab + go0, &sA[c0 * 8]);
        gl_lds16(Ab + go1, &sA[c1 * 8]);
        gl_lds16(Bb + go0, &sB[c0 * 8]);
        gl_lds16(Bb + go1, &sB[c1 * 8]);
        __syncthreads();

        half8 a[4], b[4];
        #pragma unroll
        for (int i = 0; i < 4; i++) {
            a[i] = *(const half8*)&sA[(wy * 64 + i * 16 + mrow) * 32 + kgrp * 8];
            b[i] = *(const half8*)&sB[(wx * 64 + i * 16 + mrow) * 32 + kgrp * 8];
        }
        #pragma unroll
        for (int i = 0; i < 4; i++)
            #pragma unroll
            for (int j = 0; j < 4; j++)
                acc[i][j] = __builtin_amdgcn_mfma_f32_16x16x32_f16(a[i], b[j], acc[i][j], 0, 0, 0);
    }

    // epilogue. C/D layout: col = lane&15 (mrow), row = kgrp*4 + reg.
    #pragma unroll
    for (int i = 0; i < 4; i++) {
        #pragma unroll
        for (int r = 0; r < 4; r++) {
            const int lrow = l0 + wy * 64 + i * 16 + kgrp * 4 + r;
            // per-lane best over j
            float s0 = acc[i][0][r] + biasS[wx * 64 + mrow];
            float bestv = s0; int bestj = 0;
            #pragma unroll
            for (int j = 1; j < 4; j++) {
                float s = acc[i][j][r] + biasS[wx * 64 + j * 16 + mrow];
                if (s > bestv) { bestv = s; bestj = j; }
            }
            unsigned long long key = packkey(bestv, n0 + wx * 64 + bestj * 16 + mrow);
            // 16-lane group max (lanes differing in low 4 bits share kgrp)
            #pragma unroll
            for (int m = 1; m < 16; m <<= 1) {
                unsigned long long o = __shfl_xor(key, m, 64);
                if (o > key) key = o;
            }
            float thr = unsortable((unsigned)(key >> 32)) - T_MARGIN;
            // append every col in this 64-group within T of the group max
            #pragma unroll
            for (int j = 0; j < 4; j++) {
                float s = acc[i][j][r] + biasS[wx * 64 + j * 16 + mrow];
                if (s >= thr) {
                    int pos = atomicAdd(&g_cnt[lrow], 1);
                    if (pos < CAP_)
                        g_list[(size_t)lrow * CAP_ + pos] =
                            packkey(s, n0 + wx * 64 + j * 16 + mrow);
                }
            }
        }
    }
}

// ---- per-row shortlist + exact fp32 rescore ---------------------------------
__global__ __launch_bounds__(256)
void reduce_rescue(const float* __restrict__ img, const float* __restrict__ mem)
{
    const int l = blockIdx.x;
    const int tid = threadIdx.x;
    const int lane = tid & 63, wave = tid >> 6;

    __shared__ unsigned long long redk[4];
    __shared__ float redf[4];
    __shared__ int   scand[SCAP_];
    __shared__ int   scnt;

    if (tid == 0) scnt = 0;
    int cnt = g_cnt[l];
    bool full = cnt > CAP_;
    __syncthreads();

    if (!full) {
        int k = cnt;
        const unsigned long long* lst = g_list + (size_t)l * CAP_;
        // row max over candidate list
        unsigned long long mk = 0ull;
        for (int q = tid; q < k; q += 256) {
            unsigned long long e = lst[q];
            if (e > mk) mk = e;
        }
        #pragma unroll
        for (int m = 32; m >= 1; m >>= 1) {
            unsigned long long o = __shfl_xor(mk, m, 64);
            if (o > mk) mk = o;
        }
        if (lane == 0) redk[wave] = mk;
        __syncthreads();
        unsigned long long rowk = redk[0];
        #pragma unroll
        for (int w = 1; w < 4; w++) if (redk[w] > rowk) rowk = redk[w];
        float thr = unsortable((unsigned)(rowk >> 32)) - T_MARGIN;
        // shortlist: approx score within T of row max
        for (int q = tid; q < k; q += 256) {
            unsigned long long e = lst[q];
            if (unsortable((unsigned)(e >> 32)) >= thr) {
                int p = atomicAdd(&scnt, 1);
                if (p < SCAP_) scand[p] = (int)(~(unsigned)(e & 0xFFFFFFFFull));
            }
        }
    }
    __syncthreads();
    int kk; bool scanall = full || (scnt > SCAP_);
    kk = scanall ? NMEM_ : scnt;

    // exact fp32 rescore of the shortlist (expected ~1.4 entries)
    const int py = l / LWID, px = l - (l / LWID) * LWID;
    float bestv = -3.4e38f; int bestn = 0x7FFFFFFF;
    for (int q = 0; q < kk; q++) {
        int n = scanall ? q : scand[q];
        const float* mr = mem + (size_t)n * D_;
        float s = 0.f;
        for (int d = tid; d < D_; d += 256) {
            int c = d >> 10, rem = d & 1023, kh = rem >> 5, kw = rem & 31;
            int y = py + kh - PAD_, x = px + kw - PAD_;
            float p = ((unsigned)y < (unsigned)H_ && (unsigned)x < (unsigned)W_)
                      ? img[((size_t)y * W_ + x) * C_ + c] : 0.f;
            s = fmaf(p, mr[d], s);
        }
        #pragma unroll
        for (int sh = 32; sh >= 1; sh >>= 1) s += __shfl_xor(s, sh, 64);
        if (lane == 0) redf[wave] = s;
        __syncthreads();
        float tot = redf[0] + redf[1] + redf[2] + redf[3] + g_bias[n];
        __syncthreads();   // redf reused next iteration
        if (tot > bestv || (tot == bestv && n < bestn)) { bestv = tot; bestn = n; }
    }
    if (tid == 0) g_best[l] = bestn;
}

// ---- fold: scatter mem2[mapping[ks]] straight into the cropped output -------
// Block index swizzled by a coprime stride so concurrently-resident blocks
// write far-apart image regions (less same-address atomic serialization).
__global__ __launch_bounds__(256)
void fold_scatter(const int* __restrict__ mapping,
                  const float* __restrict__ mem2,
                  float* __restrict__ out)
{
    int l = (int)(((long long)blockIdx.x * 8191) % L_);   // gcd(8191, 13689)=1
    int n = g_best[l];
    int pat = mapping[n];
    const float* row = mem2 + (size_t)pat * D_;
    int py = l / LWID, px = l - (l / LWID) * LWID;
    for (int d = threadIdx.x; d < D_; d += 256) {
        int c = d >> 10, rem = d & 1023, kh = rem >> 5, kw = rem & 31;
        int y = py + kh - PAD_;
        int x = px + kw - PAD_;
        if ((unsigned)y < (unsigned)H_ && (unsigned)x < (unsigned)W_)
            atomicAdd(out + ((size_t)y * W_ + x) * C_ + c, row[d]);
    }
}

// ---- global max over out ----------------------------------------------------
__global__ __launch_bounds__(256)
void maxfind(const float* __restrict__ out)
{
    int i = blockIdx.x * 256 + threadIdx.x;
    float v = (i < H_ * W_ * C_) ? out[i] : -3.4e38f;
    #pragma unroll
    for (int s = 32; s >= 1; s >>= 1) v = fmaxf(v, __shfl_xor(v, s, 64));
    if ((threadIdx.x & 63) == 0) atomicMax(&g_max, sortable(v));
}

__global__ __launch_bounds__(256)
void normalize_k(float* __restrict__ out)
{
    int i = blockIdx.x * 256 + threadIdx.x;
    if (i >= H_ * W_ * C_) return;
    float mx = unsortable(g_max);
    out[i] = out[i] / mx;
}

extern "C" void kernel_launch(void* const* d_in, const int* in_sizes, int n_in,
                              void* d_out, int out_size, void* d_ws, size_t ws_size,
                              hipStream_t stream)
{
    const float* img     = (const float*)d_in[0];   // (128,128,3)
    const float* mem     = (const float*)d_in[1];   // (4096,3072)
    const float* mem2    = (const float*)d_in[2];   // (4096,3072)
    const int*   mapping = (const int*)d_in[3];     // (4096,)
    float* out = (float*)d_out;                     // (128,128,3)

    // d_out is poisoned 0xAA before every launch — zero it (fold accumulates).
    hipMemsetAsync(d_out, 0, (size_t)out_size * sizeof(float), stream);

    init_kernel<<<(LPAD + 255) / 256, 256, 0, stream>>>();
    split_mem<<<NMEM_, 256, 0, stream>>>(mem);
    build_patches<<<LPAD, 256, 0, stream>>>(img);
    gemm_scores<<<dim3(NMEM_ / 128, LPAD / 128), 256, 0, stream>>>();
    reduce_rescue<<<L_, 256, 0, stream>>>(img, mem);
    fold_scatter<<<L_, 256, 0, stream>>>(mapping, mem2, out);
    maxfind<<<(H_ * W_ * C_ + 255) / 256, 256, 0, stream>>>(out);
    normalize_k<<<(H_ * W_ * C_ + 255) / 256, 256, 0, stream>>>(out);
}